// Round 14
// baseline (173.902 us; speedup 1.0000x reference)
//
#include <hip/hip_runtime.h>
#include <hip/hip_cooperative_groups.h>

namespace cg = cooperative_groups;

#define N_NODES 100000
#define N_EDGES 1600000
#define IN_F 256
#define OUT_F 128
#define E4 (N_EDGES / 4)

#define BUCKETS 256
#define NPB 391                        // 256*391 = 100096 >= N_NODES
#define CAP 8192                       // slab capacity/bucket (mean 6250, +24 sd)
#define CH2 6272                       // edges per partition chunk (256 chunks)

#define GEMM_TILES 782                 // 782 * 128 rows >= N_NODES
#define NITEMS (BUCKETS + GEMM_TILES)  // 1038 work items in phase 2

typedef short bf16x8 __attribute__((ext_vector_type(8)));
typedef float f32x4 __attribute__((ext_vector_type(4)));

// ---- bf16 helpers (RNE) ----
__device__ __forceinline__ unsigned int f2bf(float f) {
    unsigned int u = __float_as_uint(f);
    return (u + 0x7FFFu + ((u >> 16) & 1u)) >> 16;
}
__device__ __forceinline__ unsigned int pack2(float a, float b) {
    return f2bf(a) | (f2bf(b) << 16);
}
__device__ __forceinline__ float bf_lo(unsigned int u) { return __uint_as_float(u << 16); }
__device__ __forceinline__ float bf_hi(unsigned int u) { return __uint_as_float(u & 0xFFFF0000u); }

// ---------------- Mega kernel: {Wfrag + partition} -> grid.sync -> {bin | gemm} ----
// 256 blocks x 512 thr, 1 block/CU (100KB LDS) -> co-resident, coop-launched.
__global__ __launch_bounds__(512) void mega_kernel(const float* __restrict__ feat,
                                                   const float* __restrict__ W,
                                                   unsigned short* __restrict__ Wfrag,
                                                   const float* __restrict__ cj,
                                                   unsigned short* __restrict__ h,
                                                   const int* __restrict__ src,
                                                   const int* __restrict__ dst,
                                                   int* __restrict__ bucket_cursor,
                                                   int* __restrict__ wsctr,
                                                   unsigned int* __restrict__ slab,
                                                   int* __restrict__ offsets,
                                                   int* __restrict__ bin_src) {
    __shared__ __align__(16) char pool[65536 + 8 * 16 * 136 * 2];   // 100352 B
    __shared__ int item_sh;

    const int bid = blockIdx.x;
    const int tid = threadIdx.x;

    // ================= Phase 1: Wfrag prep + edge partition =================
    {
        int* hist   = (int*)pool;                       // 256
        int* hstart = hist + 256;                       // 256
        int* gbase  = hstart + 256;                     // 256
        unsigned int* stage = (unsigned int*)(gbase + 256);      // CH2 (25088 B)
        unsigned char* bstage = (unsigned char*)(stage + CH2);   // CH2 (6272 B)

        // fragment-ordered bf16 W: 128 entries per block
        if (tid < 128) {
            int idx = bid * 128 + tid;
            int j    = idx & 7;
            int lane = (idx >> 3) & 63;
            int fkt  = idx >> 9;
            int f    = fkt >> 3;
            int kt   = fkt & 7;
            int c    = f * 16 + (lane & 15);
            int k    = kt * 32 + (lane >> 4) * 8 + j;
            Wfrag[idx] = (unsigned short)f2bf(W[k * OUT_F + c]);
        }

        const int e0 = bid * CH2;
        int nE = N_EDGES - e0;
        if (nE > CH2) nE = CH2;
        if (nE < 0) nE = 0;

        if (tid < 256) hist[tid] = 0;
        __syncthreads();

        int bb[16], rr[16];
        unsigned int pp[16];
        const int4* d4 = reinterpret_cast<const int4*>(dst);
        const int4* s4 = reinterpret_cast<const int4*>(src);
        #pragma unroll
        for (int i = 0; i < 4; ++i) {
            int li = tid + i * 512;             // int4 index within chunk (<1568)
            if (li * 4 < nE) {
                int4 d = d4[(e0 >> 2) + li];
                int4 s = s4[(e0 >> 2) + li];
                int b0 = d.x / NPB, b1 = d.y / NPB, b2 = d.z / NPB, b3 = d.w / NPB;
                bb[i*4+0] = b0; pp[i*4+0] = ((unsigned)(d.x - b0 * NPB) << 17) | (unsigned)s.x;
                bb[i*4+1] = b1; pp[i*4+1] = ((unsigned)(d.y - b1 * NPB) << 17) | (unsigned)s.y;
                bb[i*4+2] = b2; pp[i*4+2] = ((unsigned)(d.z - b2 * NPB) << 17) | (unsigned)s.z;
                bb[i*4+3] = b3; pp[i*4+3] = ((unsigned)(d.w - b3 * NPB) << 17) | (unsigned)s.w;
                rr[i*4+0] = atomicAdd(&hist[b0], 1);
                rr[i*4+1] = atomicAdd(&hist[b1], 1);
                rr[i*4+2] = atomicAdd(&hist[b2], 1);
                rr[i*4+3] = atomicAdd(&hist[b3], 1);
            } else {
                bb[i*4+0] = -1; bb[i*4+1] = -1; bb[i*4+2] = -1; bb[i*4+3] = -1;
            }
        }
        __syncthreads();

        int v = 0;
        if (tid < 256) { v = hist[tid]; hstart[tid] = v; }
        __syncthreads();
        #pragma unroll
        for (int off = 1; off < 256; off <<= 1) {
            int u = 0;
            if (tid < 256 && tid >= off) u = hstart[tid - off];
            __syncthreads();
            if (tid < 256) hstart[tid] += u;
            __syncthreads();
        }
        if (tid < 256) {
            int ex = hstart[tid] - v;
            if (v > 0) gbase[tid] = atomicAdd(&bucket_cursor[tid], v);
            hstart[tid] = ex;
        }
        __syncthreads();

        #pragma unroll
        for (int i = 0; i < 16; ++i) {
            if (bb[i] >= 0) {
                int pos = hstart[bb[i]] + rr[i];
                stage[pos] = pp[i];
                bstage[pos] = (unsigned char)bb[i];
            }
        }
        __syncthreads();

        // burst copy: consecutive idx -> consecutive slab addresses per bucket run
        for (int idx = tid; idx < nE; idx += 512) {
            int b = bstage[idx];
            slab[(size_t)b * CAP + gbase[b] + (idx - hstart[b])] = stage[idx];
        }
    }

    cg::this_grid().sync();

    // ================= Phase 2: work-stealing {bin buckets | gemm tiles} =====
    unsigned short* wl = (unsigned short*)pool;                     // 64 KB Wfrag
    const int wave = tid >> 6;
    const int lane = tid & 63;
    const int r  = lane & 15;
    const int kq = lane >> 4;

    // stage Wfrag -> LDS once per block
    {
        const uint4* wsrc = reinterpret_cast<const uint4*>(Wfrag);
        uint4* wdst = reinterpret_cast<uint4*>(wl);
        #pragma unroll
        for (int i = 0; i < 8; ++i) wdst[tid + i * 512] = wsrc[tid + i * 512];
    }
    __syncthreads();

    for (;;) {
        if (tid == 0) item_sh = atomicAdd(wsctr, 1);
        __syncthreads();
        const int item = item_sh;
        if (item >= NITEMS) break;

        if (item < BUCKETS) {
            // ---- bin item: bucket b ----
            int* hist = (int*)(pool + 65536);      // 392
            int* cur  = hist + 392;                // 392
            int* sbuf = cur + 392;                 // 512
            int* gbsz = sbuf + 512;                // 2

            const int b = item;
            const int nlo = b * NPB;
            int nn = N_NODES - nlo;
            if (nn > NPB) nn = NPB;

            int v = (tid < 256) ? bucket_cursor[tid] : 0;
            sbuf[tid] = v;
            __syncthreads();
            #pragma unroll
            for (int off = 1; off < 512; off <<= 1) {
                int u = (tid >= off) ? sbuf[tid - off] : 0;
                __syncthreads();
                sbuf[tid] += u;
                __syncthreads();
            }
            if (tid == b) { gbsz[0] = sbuf[tid] - v; gbsz[1] = v; }
            if (b == 0 && tid == 0) offsets[N_NODES] = N_EDGES;
            __syncthreads();
            const int gb = gbsz[0];
            const int sz = gbsz[1];
            const unsigned int* sl = slab + (size_t)b * CAP;

            for (int j = tid; j < 392; j += 512) hist[j] = 0;
            __syncthreads();

            for (int i = tid; i < sz; i += 512) atomicAdd(&hist[sl[i] >> 17], 1);
            __syncthreads();

            int hv = (tid < 391) ? hist[tid] : 0;
            sbuf[tid] = hv;
            __syncthreads();
            #pragma unroll
            for (int off = 1; off < 512; off <<= 1) {
                int u = (tid >= off) ? sbuf[tid - off] : 0;
                __syncthreads();
                sbuf[tid] += u;
                __syncthreads();
            }
            if (tid < nn) {
                int o = gb + sbuf[tid] - hv;
                offsets[nlo + tid] = o;
                cur[tid] = o;
            }
            __syncthreads();

            for (int i = tid; i < sz; i += 512) {
                unsigned int p = sl[i];
                int pos = atomicAdd(&cur[p >> 17], 1);
                bin_src[pos] = (int)(p & 0x1FFFFu);
            }
        } else {
            // ---- gemm item: 128-row tile g ----
            const int g = item - BUCKETS;
            const int rowbase = g * 128 + wave * 16;
            unsigned short* wout = (unsigned short*)(pool + 65536) + wave * (16 * 136);

            int arow = rowbase + r;
            if (arow >= N_NODES) arow = N_NODES - 1;
            const float4* fr4 = reinterpret_cast<const float4*>(feat + (size_t)arow * IN_F);

            float4 fv[16];
            #pragma unroll
            for (int kt = 0; kt < 8; ++kt) {
                fv[2 * kt]     = fr4[kt * 8 + kq * 2];
                fv[2 * kt + 1] = fr4[kt * 8 + kq * 2 + 1];
            }

            bf16x8 a[8];
            #pragma unroll
            for (int kt = 0; kt < 8; ++kt) {
                uint4 au;
                au.x = pack2(fv[2 * kt].x,     fv[2 * kt].y);
                au.y = pack2(fv[2 * kt].z,     fv[2 * kt].w);
                au.z = pack2(fv[2 * kt + 1].x, fv[2 * kt + 1].y);
                au.w = pack2(fv[2 * kt + 1].z, fv[2 * kt + 1].w);
                a[kt] = *reinterpret_cast<bf16x8*>(&au);
            }

            f32x4 acc[8];
            #pragma unroll
            for (int f = 0; f < 8; ++f) acc[f] = (f32x4){0.f, 0.f, 0.f, 0.f};

            #pragma unroll
            for (int kt = 0; kt < 8; ++kt) {
                #pragma unroll
                for (int f = 0; f < 8; ++f) {
                    bf16x8 b = *reinterpret_cast<const bf16x8*>(&wl[((f * 8 + kt) * 64 + lane) * 8]);
                    acc[f] = __builtin_amdgcn_mfma_f32_16x16x32_bf16(a[kt], b, acc[f], 0, 0, 0);
                }
            }

            int orow[4]; float cjv[4];
            #pragma unroll
            for (int i = 0; i < 4; ++i) {
                orow[i] = rowbase + kq * 4 + i;
                cjv[i] = cj[orow[i] < N_NODES ? orow[i] : 0];
            }

            #pragma unroll
            for (int f = 0; f < 8; ++f) {
                #pragma unroll
                for (int i = 0; i < 4; ++i) {
                    wout[(kq * 4 + i) * 136 + f * 16 + r] =
                        (unsigned short)f2bf(acc[f][i] * cjv[i]);
                }
            }
            __syncthreads();   // wout transpose visibility

            {
                int row = lane >> 2;
                int ch  = lane & 3;
                int grow = rowbase + row;
                if (grow < N_NODES) {
                    uint4* hv4 = reinterpret_cast<uint4*>(h);
                    #pragma unroll
                    for (int j = 0; j < 4; ++j) {
                        uint4 vv = *reinterpret_cast<const uint4*>(
                            (const char*)wout + row * 272 + (ch + 4 * j) * 16);
                        hv4[(size_t)grow * 16 + ch + 4 * j] = vv;
                    }
                }
            }
        }
        __syncthreads();   // LDS scratch reuse across items
    }
}

// ---------------- Gather: 16 lanes/node, uint4 per lane (unchanged) -----------
__global__ __launch_bounds__(256) void gather_kernel(const uint4* __restrict__ h4,
                                                     const float* __restrict__ ci,
                                                     const int* __restrict__ offsets,
                                                     const int* __restrict__ bin_src,
                                                     float* __restrict__ out) {
    int node = blockIdx.x * 16 + (threadIdx.x >> 4);
    int lane = threadIdx.x & 15;
    if (node >= N_NODES) return;

    int beg = offsets[node];
    int end = offsets[node + 1];

    float acc[8] = {};
    int i = beg;
    for (; i + 4 <= end; i += 4) {
        int s0 = bin_src[i + 0];
        int s1 = bin_src[i + 1];
        int s2 = bin_src[i + 2];
        int s3 = bin_src[i + 3];
        uint4 v0 = h4[(size_t)s0 * 16 + lane];
        uint4 v1 = h4[(size_t)s1 * 16 + lane];
        uint4 v2 = h4[(size_t)s2 * 16 + lane];
        uint4 v3 = h4[(size_t)s3 * 16 + lane];
        acc[0] += (bf_lo(v0.x) + bf_lo(v1.x)) + (bf_lo(v2.x) + bf_lo(v3.x));
        acc[1] += (bf_hi(v0.x) + bf_hi(v1.x)) + (bf_hi(v2.x) + bf_hi(v3.x));
        acc[2] += (bf_lo(v0.y) + bf_lo(v1.y)) + (bf_lo(v2.y) + bf_lo(v3.y));
        acc[3] += (bf_hi(v0.y) + bf_hi(v1.y)) + (bf_hi(v2.y) + bf_hi(v3.y));
        acc[4] += (bf_lo(v0.z) + bf_lo(v1.z)) + (bf_lo(v2.z) + bf_lo(v3.z));
        acc[5] += (bf_hi(v0.z) + bf_hi(v1.z)) + (bf_hi(v2.z) + bf_hi(v3.z));
        acc[6] += (bf_lo(v0.w) + bf_lo(v1.w)) + (bf_lo(v2.w) + bf_lo(v3.w));
        acc[7] += (bf_hi(v0.w) + bf_hi(v1.w)) + (bf_hi(v2.w) + bf_hi(v3.w));
    }
    for (; i < end; ++i) {
        int s = bin_src[i];
        uint4 v = h4[(size_t)s * 16 + lane];
        acc[0] += bf_lo(v.x); acc[1] += bf_hi(v.x);
        acc[2] += bf_lo(v.y); acc[3] += bf_hi(v.y);
        acc[4] += bf_lo(v.z); acc[5] += bf_hi(v.z);
        acc[6] += bf_lo(v.w); acc[7] += bf_hi(v.w);
    }
    float sc = ci[node];
    float4 o0 = make_float4(acc[0] * sc, acc[1] * sc, acc[2] * sc, acc[3] * sc);
    float4 o1 = make_float4(acc[4] * sc, acc[5] * sc, acc[6] * sc, acc[7] * sc);
    float4* o4 = reinterpret_cast<float4*>(out) + (size_t)node * 32 + lane * 2;
    o4[0] = o0;
    o4[1] = o1;
}

extern "C" void kernel_launch(void* const* d_in, const int* in_sizes, int n_in,
                              void* d_out, int out_size, void* d_ws, size_t ws_size,
                              hipStream_t stream) {
    const float* feat = (const float*)d_in[0];
    const float* W    = (const float*)d_in[1];
    const float* cj   = (const float*)d_in[2];
    const float* ci   = (const float*)d_in[3];
    const int*   src  = (const int*)d_in[4];
    const int*   dst  = (const int*)d_in[5];
    float* out = (float*)d_out;

    const size_t H_BYTES    = (size_t)N_NODES * OUT_F * 2;          // 25.6 MB
    const size_t WT_BYTES   = (size_t)IN_F * OUT_F * 2;             // 64 KB
    const size_t OFF_BYTES  = (((size_t)(N_NODES + 1) * 4) + 15) & ~(size_t)15;
    const size_t CTR_BYTES  = (((size_t)(BUCKETS + 4) * 4) + 15) & ~(size_t)15;
    const size_t SLAB_BYTES = (size_t)BUCKETS * CAP * 4;            // 8 MB (packed)

    char* ws = (char*)d_ws;
    unsigned short* h     = (unsigned short*)ws;  ws += H_BYTES;
    unsigned short* Wfrag = (unsigned short*)ws;  ws += WT_BYTES;
    int* offsets        = (int*)ws;           ws += OFF_BYTES;
    int* bucket_cursor  = (int*)ws;           ws += CTR_BYTES;
    unsigned int* slab  = (unsigned int*)ws;  ws += SLAB_BYTES;
    int* bin_src        = (int*)ws;
    int* wsctr          = bucket_cursor + BUCKETS;

    // zero bucket cursors + work-stealing counter
    hipMemsetAsync(bucket_cursor, 0, (size_t)(BUCKETS + 4) * 4, stream);

    void* args[] = {(void*)&feat, (void*)&W, (void*)&Wfrag, (void*)&cj, (void*)&h,
                    (void*)&src, (void*)&dst, (void*)&bucket_cursor, (void*)&wsctr,
                    (void*)&slab, (void*)&offsets, (void*)&bin_src};
    hipLaunchCooperativeKernel((void*)mega_kernel, dim3(256), dim3(512), args, 0, stream);

    gather_kernel<<<(N_NODES + 15) / 16, 256, 0, stream>>>((const uint4*)h, ci, offsets, bin_src, out);
}

// Round 15
// 127.541 us; speedup vs baseline: 1.3635x; 1.3635x over previous
//
#include <hip/hip_runtime.h>

#define N_NODES 100000
#define N_EDGES 1600000
#define IN_F 256
#define OUT_F 128
#define E4 (N_EDGES / 4)

#define BUCKETS 256
#define NPB 391                        // 256*391 = 100096 >= N_NODES
#define CH 8192
#define NCHUNK ((N_EDGES + CH - 1) / CH)   // 196
#define CAP 8192                       // slab capacity/bucket (mean 6250, +24 sd)

#define GEMM_BLOCKS 1563               // 1563 * 64 rows = 100032 >= N_NODES
#define GB_BLOCKS (GEMM_BLOCKS + BUCKETS)  // 1819

typedef short bf16x8 __attribute__((ext_vector_type(8)));
typedef float f32x4 __attribute__((ext_vector_type(4)));

// ---- bf16 helpers (RNE) ----
__device__ __forceinline__ unsigned int f2bf(float f) {
    unsigned int u = __float_as_uint(f);
    return (u + 0x7FFFu + ((u >> 16) & 1u)) >> 16;
}
__device__ __forceinline__ unsigned int pack2(float a, float b) {
    return f2bf(a) | (f2bf(b) << 16);
}
__device__ __forceinline__ float bf_lo(unsigned int u) { return __uint_as_float(u << 16); }
__device__ __forceinline__ float bf_hi(unsigned int u) { return __uint_as_float(u & 0xFFFF0000u); }

// ---------------- P1: partition (+Wfrag prep in first 64 blocks) --------------
// 196 blocks x 512 thr, 8192 edges/chunk. Slab entries PACKED to 4B:
// (dstLocal<<17)|src  (dstLocal<391 fits 9 bits, src<100000 fits 17 bits).
// LDS 43KB -> 3 blocks/CU.
__global__ __launch_bounds__(512) void part_kernel(const float* __restrict__ W,
                                                   unsigned short* __restrict__ Wfrag,
                                                   const int* __restrict__ src,
                                                   const int* __restrict__ dst,
                                                   int* __restrict__ bucket_cursor,
                                                   unsigned int* __restrict__ slab) {
    __shared__ int hist[256];
    __shared__ int hstart[256];
    __shared__ int gbase[256];
    __shared__ unsigned int stage[CH];      // 32 KB
    __shared__ unsigned char bstage[CH];    // 8 KB

    const int bid = blockIdx.x;
    const int t = threadIdx.x;

    // fragment-ordered bf16 W: 64 blocks x 512 entries = 32768
    if (bid < 64) {
        int idx = bid * 512 + t;
        int j    = idx & 7;
        int lane = (idx >> 3) & 63;
        int fkt  = idx >> 9;
        int f    = fkt >> 3;
        int kt   = fkt & 7;
        int c    = f * 16 + (lane & 15);
        int k    = kt * 32 + (lane >> 4) * 8 + j;
        Wfrag[idx] = (unsigned short)f2bf(W[k * OUT_F + c]);
    }

    const int e0 = bid * CH;
    int nE = N_EDGES - e0;
    if (nE > CH) nE = CH;
    if (nE < 0) nE = 0;

    if (t < 256) hist[t] = 0;
    __syncthreads();

    int bb[16], rr[16];
    unsigned int pp[16];
    const int4* d4 = reinterpret_cast<const int4*>(dst);
    const int4* s4 = reinterpret_cast<const int4*>(src);
    #pragma unroll
    for (int i = 0; i < 4; ++i) {
        int li = t + i * 512;
        if (li * 4 < nE) {
            int4 d = d4[(e0 >> 2) + li];
            int4 s = s4[(e0 >> 2) + li];
            int b0 = d.x / NPB, b1 = d.y / NPB, b2 = d.z / NPB, b3 = d.w / NPB;
            bb[i*4+0] = b0; pp[i*4+0] = ((unsigned)(d.x - b0 * NPB) << 17) | (unsigned)s.x;
            bb[i*4+1] = b1; pp[i*4+1] = ((unsigned)(d.y - b1 * NPB) << 17) | (unsigned)s.y;
            bb[i*4+2] = b2; pp[i*4+2] = ((unsigned)(d.z - b2 * NPB) << 17) | (unsigned)s.z;
            bb[i*4+3] = b3; pp[i*4+3] = ((unsigned)(d.w - b3 * NPB) << 17) | (unsigned)s.w;
            rr[i*4+0] = atomicAdd(&hist[b0], 1);
            rr[i*4+1] = atomicAdd(&hist[b1], 1);
            rr[i*4+2] = atomicAdd(&hist[b2], 1);
            rr[i*4+3] = atomicAdd(&hist[b3], 1);
        } else {
            bb[i*4+0] = -1; bb[i*4+1] = -1; bb[i*4+2] = -1; bb[i*4+3] = -1;
        }
    }
    __syncthreads();

    int v = 0;
    if (t < 256) { v = hist[t]; hstart[t] = v; }
    __syncthreads();
    #pragma unroll
    for (int off = 1; off < 256; off <<= 1) {
        int u = 0;
        if (t < 256 && t >= off) u = hstart[t - off];
        __syncthreads();
        if (t < 256) hstart[t] += u;
        __syncthreads();
    }
    if (t < 256) {
        int ex = hstart[t] - v;
        if (v > 0) gbase[t] = atomicAdd(&bucket_cursor[t], v);
        hstart[t] = ex;
    }
    __syncthreads();

    #pragma unroll
    for (int i = 0; i < 16; ++i) {
        if (bb[i] >= 0) {
            int pos = hstart[bb[i]] + rr[i];
            stage[pos] = pp[i];
            bstage[pos] = (unsigned char)bb[i];
        }
    }
    __syncthreads();

    for (int idx = t; idx < nE; idx += 512) {
        int b = bstage[idx];
        slab[(size_t)b * CAP + gbase[b] + (idx - hstart[b])] = stage[idx];
    }
}

// ---------------- Fused: MFMA gemm (bids 0..1562) + bin (bids 1563..1818) -----
// gemm role: 256 thr = 4 waves, 64 rows/block. NO W-in-LDS: b-frags read
//   directly from L2-resident Wfrag (coalesced 1KB/wave loads). LDS = 17KB
//   epilogue staging only -> ~16 waves/CU occupancy (2x r13).
// bin role: 256 thr, per-bucket; self-scans bucket sizes; packed slab.
__global__ __launch_bounds__(256) void gemm_bin_kernel(const float* __restrict__ feat,
                                                       const unsigned short* __restrict__ Wfrag,
                                                       const float* __restrict__ cj,
                                                       unsigned short* __restrict__ h,
                                                       const unsigned int* __restrict__ slab,
                                                       const int* __restrict__ bucket_cursor,
                                                       int* __restrict__ offsets,
                                                       int* __restrict__ bin_src) {
    __shared__ __align__(16) char pool[4 * 16 * 136 * 2];   // 17408 B

    const int bid = blockIdx.x;
    const int tid = threadIdx.x;

    if (bid >= GEMM_BLOCKS) {
        // ---- bin role ----
        int* hist = (int*)pool;            // 392
        int* cur  = hist + 392;            // 392
        int* sbuf = cur + 392;             // 256
        int* gbsz = sbuf + 256;            // 2

        const int b = bid - GEMM_BLOCKS;
        const int nlo = b * NPB;
        int nn = N_NODES - nlo;
        if (nn > NPB) nn = NPB;

        int v = bucket_cursor[tid];
        sbuf[tid] = v;
        __syncthreads();
        #pragma unroll
        for (int off = 1; off < 256; off <<= 1) {
            int u = (tid >= off) ? sbuf[tid - off] : 0;
            __syncthreads();
            sbuf[tid] += u;
            __syncthreads();
        }
        if (tid == b) { gbsz[0] = sbuf[tid] - v; gbsz[1] = v; }
        if (b == 0 && tid == 0) offsets[N_NODES] = N_EDGES;
        __syncthreads();
        const int gb = gbsz[0];
        const int sz = gbsz[1];
        const unsigned int* sl = slab + (size_t)b * CAP;

        for (int j = tid; j < 392; j += 256) hist[j] = 0;
        __syncthreads();

        for (int i = tid; i < sz; i += 256) atomicAdd(&hist[sl[i] >> 17], 1);
        __syncthreads();

        int a0 = 0, a1 = 0;
        if (tid < 196) { a0 = hist[2 * tid]; a1 = hist[2 * tid + 1]; }
        int part = a0 + a1;
        sbuf[tid] = part;
        __syncthreads();
        #pragma unroll
        for (int off = 1; off < 256; off <<= 1) {
            int u = (tid >= off) ? sbuf[tid - off] : 0;
            __syncthreads();
            sbuf[tid] += u;
            __syncthreads();
        }
        int ex = sbuf[tid] - part;
        if (tid < 196) {
            int o0 = gb + ex;
            int o1 = o0 + a0;
            if (2 * tid < nn)     { offsets[nlo + 2 * tid]     = o0; cur[2 * tid]     = o0; }
            if (2 * tid + 1 < nn) { offsets[nlo + 2 * tid + 1] = o1; cur[2 * tid + 1] = o1; }
        }
        __syncthreads();

        for (int i = tid; i < sz; i += 256) {
            unsigned int p = sl[i];
            int pos = atomicAdd(&cur[p >> 17], 1);
            bin_src[pos] = (int)(p & 0x1FFFFu);
        }
        return;
    }

    // ---- gemm role: 64 rows, 4 waves x 16 rows ----
    const int wave = tid >> 6;
    const int lane = tid & 63;
    const int r  = lane & 15;
    const int kq = lane >> 4;
    const int rowbase = bid * 64 + wave * 16;
    unsigned short* wout = (unsigned short*)pool + wave * (16 * 136);

    int arow = rowbase + r;
    if (arow >= N_NODES) arow = N_NODES - 1;
    const float4* fr4 = reinterpret_cast<const float4*>(feat + (size_t)arow * IN_F);

    // feat load+convert in two 8-float4 chunks (limits VGPR pressure)
    bf16x8 a[8];
    #pragma unroll
    for (int c = 0; c < 2; ++c) {
        float4 fv[8];
        #pragma unroll
        for (int kt = 0; kt < 4; ++kt) {
            fv[2 * kt]     = fr4[(c * 4 + kt) * 8 + kq * 2];
            fv[2 * kt + 1] = fr4[(c * 4 + kt) * 8 + kq * 2 + 1];
        }
        #pragma unroll
        for (int kt = 0; kt < 4; ++kt) {
            uint4 au;
            au.x = pack2(fv[2 * kt].x,     fv[2 * kt].y);
            au.y = pack2(fv[2 * kt].z,     fv[2 * kt].w);
            au.z = pack2(fv[2 * kt + 1].x, fv[2 * kt + 1].y);
            au.w = pack2(fv[2 * kt + 1].z, fv[2 * kt + 1].w);
            a[c * 4 + kt] = *reinterpret_cast<bf16x8*>(&au);
        }
    }

    f32x4 acc[8];
    #pragma unroll
    for (int f = 0; f < 8; ++f) acc[f] = (f32x4){0.f, 0.f, 0.f, 0.f};

    // b-frags straight from L2-resident Wfrag (coalesced, 8 independent/kt)
    #pragma unroll
    for (int kt = 0; kt < 8; ++kt) {
        #pragma unroll
        for (int f = 0; f < 8; ++f) {
            bf16x8 b = *reinterpret_cast<const bf16x8*>(Wfrag + ((f * 8 + kt) * 64 + lane) * 8);
            acc[f] = __builtin_amdgcn_mfma_f32_16x16x32_bf16(a[kt], b, acc[f], 0, 0, 0);
        }
    }

    int orow[4]; float cjv[4];
    #pragma unroll
    for (int i = 0; i < 4; ++i) {
        orow[i] = rowbase + kq * 4 + i;
        cjv[i] = cj[orow[i] < N_NODES ? orow[i] : 0];
    }

    #pragma unroll
    for (int f = 0; f < 8; ++f) {
        #pragma unroll
        for (int i = 0; i < 4; ++i) {
            wout[(kq * 4 + i) * 136 + f * 16 + r] =
                (unsigned short)f2bf(acc[f][i] * cjv[i]);
        }
    }
    __syncthreads();

    {
        int row = lane >> 2;
        int ch  = lane & 3;
        int grow = rowbase + row;
        if (grow < N_NODES) {
            uint4* hv = reinterpret_cast<uint4*>(h);
            #pragma unroll
            for (int j = 0; j < 4; ++j) {
                uint4 vv = *reinterpret_cast<const uint4*>(
                    (const char*)wout + row * 272 + (ch + 4 * j) * 16);
                hv[(size_t)grow * 16 + ch + 4 * j] = vv;
            }
        }
    }
}

// ---------------- Gather: 16 lanes/node, uint4 per lane (unchanged) -----------
__global__ __launch_bounds__(256) void gather_kernel(const uint4* __restrict__ h4,
                                                     const float* __restrict__ ci,
                                                     const int* __restrict__ offsets,
                                                     const int* __restrict__ bin_src,
                                                     float* __restrict__ out) {
    int node = blockIdx.x * 16 + (threadIdx.x >> 4);
    int lane = threadIdx.x & 15;
    if (node >= N_NODES) return;

    int beg = offsets[node];
    int end = offsets[node + 1];

    float acc[8] = {};
    int i = beg;
    for (; i + 4 <= end; i += 4) {
        int s0 = bin_src[i + 0];
        int s1 = bin_src[i + 1];
        int s2 = bin_src[i + 2];
        int s3 = bin_src[i + 3];
        uint4 v0 = h4[(size_t)s0 * 16 + lane];
        uint4 v1 = h4[(size_t)s1 * 16 + lane];
        uint4 v2 = h4[(size_t)s2 * 16 + lane];
        uint4 v3 = h4[(size_t)s3 * 16 + lane];
        acc[0] += (bf_lo(v0.x) + bf_lo(v1.x)) + (bf_lo(v2.x) + bf_lo(v3.x));
        acc[1] += (bf_hi(v0.x) + bf_hi(v1.x)) + (bf_hi(v2.x) + bf_hi(v3.x));
        acc[2] += (bf_lo(v0.y) + bf_lo(v1.y)) + (bf_lo(v2.y) + bf_lo(v3.y));
        acc[3] += (bf_hi(v0.y) + bf_hi(v1.y)) + (bf_hi(v2.y) + bf_hi(v3.y));
        acc[4] += (bf_lo(v0.z) + bf_lo(v1.z)) + (bf_lo(v2.z) + bf_lo(v3.z));
        acc[5] += (bf_hi(v0.z) + bf_hi(v1.z)) + (bf_hi(v2.z) + bf_hi(v3.z));
        acc[6] += (bf_lo(v0.w) + bf_lo(v1.w)) + (bf_lo(v2.w) + bf_lo(v3.w));
        acc[7] += (bf_hi(v0.w) + bf_hi(v1.w)) + (bf_hi(v2.w) + bf_hi(v3.w));
    }
    for (; i < end; ++i) {
        int s = bin_src[i];
        uint4 v = h4[(size_t)s * 16 + lane];
        acc[0] += bf_lo(v.x); acc[1] += bf_hi(v.x);
        acc[2] += bf_lo(v.y); acc[3] += bf_hi(v.y);
        acc[4] += bf_lo(v.z); acc[5] += bf_hi(v.z);
        acc[6] += bf_lo(v.w); acc[7] += bf_hi(v.w);
    }
    float sc = ci[node];
    float4 o0 = make_float4(acc[0] * sc, acc[1] * sc, acc[2] * sc, acc[3] * sc);
    float4 o1 = make_float4(acc[4] * sc, acc[5] * sc, acc[6] * sc, acc[7] * sc);
    float4* o4 = reinterpret_cast<float4*>(out) + (size_t)node * 32 + lane * 2;
    o4[0] = o0;
    o4[1] = o1;
}

extern "C" void kernel_launch(void* const* d_in, const int* in_sizes, int n_in,
                              void* d_out, int out_size, void* d_ws, size_t ws_size,
                              hipStream_t stream) {
    const float* feat = (const float*)d_in[0];
    const float* W    = (const float*)d_in[1];
    const float* cj   = (const float*)d_in[2];
    const float* ci   = (const float*)d_in[3];
    const int*   src  = (const int*)d_in[4];
    const int*   dst  = (const int*)d_in[5];
    float* out = (float*)d_out;

    const size_t H_BYTES    = (size_t)N_NODES * OUT_F * 2;          // 25.6 MB
    const size_t WT_BYTES   = (size_t)IN_F * OUT_F * 2;             // 64 KB
    const size_t OFF_BYTES  = (((size_t)(N_NODES + 1) * 4) + 15) & ~(size_t)15;
    const size_t BC_BYTES   = (((size_t)BUCKETS * 4) + 15) & ~(size_t)15;
    const size_t SLAB_BYTES = (size_t)BUCKETS * CAP * 4;            // 8 MB (packed)

    char* ws = (char*)d_ws;
    unsigned short* h     = (unsigned short*)ws;  ws += H_BYTES;
    unsigned short* Wfrag = (unsigned short*)ws;  ws += WT_BYTES;
    int* offsets        = (int*)ws;           ws += OFF_BYTES;
    int* bucket_cursor  = (int*)ws;           ws += BC_BYTES;
    unsigned int* slab  = (unsigned int*)ws;  ws += SLAB_BYTES;
    int* bin_src        = (int*)ws;

    hipMemsetAsync(bucket_cursor, 0, (size_t)BUCKETS * 4, stream);

    part_kernel<<<NCHUNK, 512, 0, stream>>>(W, Wfrag, src, dst, bucket_cursor, slab);

    gemm_bin_kernel<<<GB_BLOCKS, 256, 0, stream>>>(feat, Wfrag, cj, h, slab,
                                                   bucket_cursor, offsets, bin_src);

    gather_kernel<<<(N_NODES + 15) / 16, 256, 0, stream>>>((const uint4*)h, ci, offsets, bin_src, out);
}

// Round 16
// 120.336 us; speedup vs baseline: 1.4451x; 1.0599x over previous
//
#include <hip/hip_runtime.h>

#define N_NODES 100000
#define N_EDGES 1600000
#define IN_F 256
#define OUT_F 128
#define E4 (N_EDGES / 4)

#define BUCKETS 256
#define NPB 391                        // 256*391 = 100096 >= N_NODES
#define CH 8192
#define NCHUNK ((N_EDGES + CH - 1) / CH)   // 196
#define CAP 8192                       // slab capacity/bucket (mean 6250, +24 sd)

#define GEMM_BLOCKS 1563               // 1563 * 64 rows = 100032 >= N_NODES
#define GB_BLOCKS (GEMM_BLOCKS + BUCKETS)  // 1819

typedef short bf16x8 __attribute__((ext_vector_type(8)));
typedef float f32x4 __attribute__((ext_vector_type(4)));

// ---- bf16 helpers (RNE) ----
__device__ __forceinline__ unsigned int f2bf(float f) {
    unsigned int u = __float_as_uint(f);
    return (u + 0x7FFFu + ((u >> 16) & 1u)) >> 16;
}
__device__ __forceinline__ unsigned int pack2(float a, float b) {
    return f2bf(a) | (f2bf(b) << 16);
}
__device__ __forceinline__ float bf_lo(unsigned int u) { return __uint_as_float(u << 16); }
__device__ __forceinline__ float bf_hi(unsigned int u) { return __uint_as_float(u & 0xFFFF0000u); }

// ---------------- P1: partition (+Wfrag prep in first 64 blocks) --------------
// Wfrag is now KT-MAJOR: idx = ((kt*8 + f)*64 + lane)*8 + j, so a K-chunk
// (2 kt = 16KB) is contiguous — gemm stages one chunk at a time in LDS.
__global__ __launch_bounds__(512) void part_kernel(const float* __restrict__ W,
                                                   unsigned short* __restrict__ Wfrag,
                                                   const int* __restrict__ src,
                                                   const int* __restrict__ dst,
                                                   int* __restrict__ bucket_cursor,
                                                   unsigned int* __restrict__ slab) {
    __shared__ int hist[256];
    __shared__ int hstart[256];
    __shared__ int gbase[256];
    __shared__ unsigned int stage[CH];      // 32 KB
    __shared__ unsigned char bstage[CH];    // 8 KB

    const int bid = blockIdx.x;
    const int t = threadIdx.x;

    // fragment-ordered bf16 W, kt-major: 64 blocks x 512 entries = 32768
    if (bid < 64) {
        int idx = bid * 512 + t;
        int j    = idx & 7;
        int lane = (idx >> 3) & 63;
        int ktf  = idx >> 9;
        int kt   = ktf >> 3;
        int f    = ktf & 7;
        int c    = f * 16 + (lane & 15);
        int k    = kt * 32 + (lane >> 4) * 8 + j;
        Wfrag[idx] = (unsigned short)f2bf(W[k * OUT_F + c]);
    }

    const int e0 = bid * CH;
    int nE = N_EDGES - e0;
    if (nE > CH) nE = CH;
    if (nE < 0) nE = 0;

    if (t < 256) hist[t] = 0;
    __syncthreads();

    int bb[16], rr[16];
    unsigned int pp[16];
    const int4* d4 = reinterpret_cast<const int4*>(dst);
    const int4* s4 = reinterpret_cast<const int4*>(src);
    #pragma unroll
    for (int i = 0; i < 4; ++i) {
        int li = t + i * 512;
        if (li * 4 < nE) {
            int4 d = d4[(e0 >> 2) + li];
            int4 s = s4[(e0 >> 2) + li];
            int b0 = d.x / NPB, b1 = d.y / NPB, b2 = d.z / NPB, b3 = d.w / NPB;
            bb[i*4+0] = b0; pp[i*4+0] = ((unsigned)(d.x - b0 * NPB) << 17) | (unsigned)s.x;
            bb[i*4+1] = b1; pp[i*4+1] = ((unsigned)(d.y - b1 * NPB) << 17) | (unsigned)s.y;
            bb[i*4+2] = b2; pp[i*4+2] = ((unsigned)(d.z - b2 * NPB) << 17) | (unsigned)s.z;
            bb[i*4+3] = b3; pp[i*4+3] = ((unsigned)(d.w - b3 * NPB) << 17) | (unsigned)s.w;
            rr[i*4+0] = atomicAdd(&hist[b0], 1);
            rr[i*4+1] = atomicAdd(&hist[b1], 1);
            rr[i*4+2] = atomicAdd(&hist[b2], 1);
            rr[i*4+3] = atomicAdd(&hist[b3], 1);
        } else {
            bb[i*4+0] = -1; bb[i*4+1] = -1; bb[i*4+2] = -1; bb[i*4+3] = -1;
        }
    }
    __syncthreads();

    int v = 0;
    if (t < 256) { v = hist[t]; hstart[t] = v; }
    __syncthreads();
    #pragma unroll
    for (int off = 1; off < 256; off <<= 1) {
        int u = 0;
        if (t < 256 && t >= off) u = hstart[t - off];
        __syncthreads();
        if (t < 256) hstart[t] += u;
        __syncthreads();
    }
    if (t < 256) {
        int ex = hstart[t] - v;
        if (v > 0) gbase[t] = atomicAdd(&bucket_cursor[t], v);
        hstart[t] = ex;
    }
    __syncthreads();

    #pragma unroll
    for (int i = 0; i < 16; ++i) {
        if (bb[i] >= 0) {
            int pos = hstart[bb[i]] + rr[i];
            stage[pos] = pp[i];
            bstage[pos] = (unsigned char)bb[i];
        }
    }
    __syncthreads();

    for (int idx = t; idx < nE; idx += 512) {
        int b = bstage[idx];
        slab[(size_t)b * CAP + gbase[b] + (idx - hstart[b])] = stage[idx];
    }
}

// ---------------- Fused: MFMA gemm (bids 0..1562) + bin (bids 1563..1818) -----
// gemm role: 256 thr = 4 waves, 64 rows. K processed in 4 chunks of 64;
//   each chunk's 16KB W slice staged to LDS; feat for chunk c+1 prefetched
//   during chunk c's MFMAs. Epilogue wout ALIASES the wl region (dead after
//   last chunk) -> LDS = 17.4KB total -> ~24 waves/CU (3x prior rounds).
// bin role: unchanged (packed slab).
__global__ __launch_bounds__(256) void gemm_bin_kernel(const float* __restrict__ feat,
                                                       const unsigned short* __restrict__ Wfrag,
                                                       const float* __restrict__ cj,
                                                       unsigned short* __restrict__ h,
                                                       const unsigned int* __restrict__ slab,
                                                       const int* __restrict__ bucket_cursor,
                                                       int* __restrict__ offsets,
                                                       int* __restrict__ bin_src) {
    __shared__ __align__(16) char pool[4 * 16 * 136 * 2];   // 17408 B

    const int bid = blockIdx.x;
    const int tid = threadIdx.x;

    if (bid >= GEMM_BLOCKS) {
        // ---- bin role ----
        int* hist = (int*)pool;            // 392
        int* cur  = hist + 392;            // 392
        int* sbuf = cur + 392;             // 256
        int* gbsz = sbuf + 256;            // 2

        const int b = bid - GEMM_BLOCKS;
        const int nlo = b * NPB;
        int nn = N_NODES - nlo;
        if (nn > NPB) nn = NPB;

        int v = bucket_cursor[tid];
        sbuf[tid] = v;
        __syncthreads();
        #pragma unroll
        for (int off = 1; off < 256; off <<= 1) {
            int u = (tid >= off) ? sbuf[tid - off] : 0;
            __syncthreads();
            sbuf[tid] += u;
            __syncthreads();
        }
        if (tid == b) { gbsz[0] = sbuf[tid] - v; gbsz[1] = v; }
        if (b == 0 && tid == 0) offsets[N_NODES] = N_EDGES;
        __syncthreads();
        const int gb = gbsz[0];
        const int sz = gbsz[1];
        const unsigned int* sl = slab + (size_t)b * CAP;

        for (int j = tid; j < 392; j += 256) hist[j] = 0;
        __syncthreads();

        for (int i = tid; i < sz; i += 256) atomicAdd(&hist[sl[i] >> 17], 1);
        __syncthreads();

        int a0 = 0, a1 = 0;
        if (tid < 196) { a0 = hist[2 * tid]; a1 = hist[2 * tid + 1]; }
        int part = a0 + a1;
        sbuf[tid] = part;
        __syncthreads();
        #pragma unroll
        for (int off = 1; off < 256; off <<= 1) {
            int u = (tid >= off) ? sbuf[tid - off] : 0;
            __syncthreads();
            sbuf[tid] += u;
            __syncthreads();
        }
        int ex = sbuf[tid] - part;
        if (tid < 196) {
            int o0 = gb + ex;
            int o1 = o0 + a0;
            if (2 * tid < nn)     { offsets[nlo + 2 * tid]     = o0; cur[2 * tid]     = o0; }
            if (2 * tid + 1 < nn) { offsets[nlo + 2 * tid + 1] = o1; cur[2 * tid + 1] = o1; }
        }
        __syncthreads();

        for (int i = tid; i < sz; i += 256) {
            unsigned int p = sl[i];
            int pos = atomicAdd(&cur[p >> 17], 1);
            bin_src[pos] = (int)(p & 0x1FFFFu);
        }
        return;
    }

    // ---- gemm role: 64 rows, 4 waves x 16 rows, K-chunked W staging ----
    unsigned short* wl = (unsigned short*)pool;   // 16 KB (aliased by wout later)
    const int wave = tid >> 6;
    const int lane = tid & 63;
    const int r  = lane & 15;
    const int kq = lane >> 4;
    const int rowbase = bid * 64 + wave * 16;

    int arow = rowbase + r;
    if (arow >= N_NODES) arow = N_NODES - 1;
    const float4* fr4 = reinterpret_cast<const float4*>(feat + (size_t)arow * IN_F);

    f32x4 acc[8];
    #pragma unroll
    for (int f = 0; f < 8; ++f) acc[f] = (f32x4){0.f, 0.f, 0.f, 0.f};

    // prefetch chunk 0 feat (kt = 0,1)
    float4 fv[4];
    fv[0] = fr4[0 * 8 + kq * 2];
    fv[1] = fr4[0 * 8 + kq * 2 + 1];
    fv[2] = fr4[1 * 8 + kq * 2];
    fv[3] = fr4[1 * 8 + kq * 2 + 1];

    const uint4* wsrc = reinterpret_cast<const uint4*>(Wfrag);
    uint4* wdst = reinterpret_cast<uint4*>(wl);

    for (int c = 0; c < 4; ++c) {
        if (c > 0) __syncthreads();          // prior chunk's wl reads done
        // stage this chunk's 16KB W slice (1024 uint4 across 256 thr)
        #pragma unroll
        for (int i = 0; i < 4; ++i) wdst[tid + i * 256] = wsrc[c * 1024 + tid + i * 256];

        // pack current feat into 2 a-frags (uses fv before prefetch clobbers)
        bf16x8 a0, a1;
        {
            uint4 au;
            au.x = pack2(fv[0].x, fv[0].y);
            au.y = pack2(fv[0].z, fv[0].w);
            au.z = pack2(fv[1].x, fv[1].y);
            au.w = pack2(fv[1].z, fv[1].w);
            a0 = *reinterpret_cast<bf16x8*>(&au);
            uint4 bu;
            bu.x = pack2(fv[2].x, fv[2].y);
            bu.y = pack2(fv[2].z, fv[2].w);
            bu.z = pack2(fv[3].x, fv[3].y);
            bu.w = pack2(fv[3].z, fv[3].w);
            a1 = *reinterpret_cast<bf16x8*>(&bu);
        }

        // prefetch next chunk's feat (in flight under MFMAs below)
        if (c < 3) {
            int ktb = (c + 1) * 2;
            fv[0] = fr4[ktb * 8 + kq * 2];
            fv[1] = fr4[ktb * 8 + kq * 2 + 1];
            fv[2] = fr4[(ktb + 1) * 8 + kq * 2];
            fv[3] = fr4[(ktb + 1) * 8 + kq * 2 + 1];
        }

        __syncthreads();                     // wl staged

        #pragma unroll
        for (int f = 0; f < 8; ++f) {
            bf16x8 b = *reinterpret_cast<const bf16x8*>(&wl[((0 * 8 + f) * 64 + lane) * 8]);
            acc[f] = __builtin_amdgcn_mfma_f32_16x16x32_bf16(a0, b, acc[f], 0, 0, 0);
        }
        #pragma unroll
        for (int f = 0; f < 8; ++f) {
            bf16x8 b = *reinterpret_cast<const bf16x8*>(&wl[((1 * 8 + f) * 64 + lane) * 8]);
            acc[f] = __builtin_amdgcn_mfma_f32_16x16x32_bf16(a1, b, acc[f], 0, 0, 0);
        }
    }

    int orow[4]; float cjv[4];
    #pragma unroll
    for (int i = 0; i < 4; ++i) {
        orow[i] = rowbase + kq * 4 + i;
        cjv[i] = cj[orow[i] < N_NODES ? orow[i] : 0];
    }

    __syncthreads();   // all wl reads done; reuse pool as wout
    unsigned short* wout = (unsigned short*)pool + wave * (16 * 136);
    #pragma unroll
    for (int f = 0; f < 8; ++f) {
        #pragma unroll
        for (int i = 0; i < 4; ++i) {
            wout[(kq * 4 + i) * 136 + f * 16 + r] =
                (unsigned short)f2bf(acc[f][i] * cjv[i]);
        }
    }
    __syncthreads();

    {
        int row = lane >> 2;
        int ch  = lane & 3;
        int grow = rowbase + row;
        if (grow < N_NODES) {
            uint4* hv = reinterpret_cast<uint4*>(h);
            #pragma unroll
            for (int j = 0; j < 4; ++j) {
                uint4 vv = *reinterpret_cast<const uint4*>(
                    (const char*)wout + row * 272 + (ch + 4 * j) * 16);
                hv[(size_t)grow * 16 + ch + 4 * j] = vv;
            }
        }
    }
}

// ---------------- Gather: 16 lanes/node, uint4 per lane (unchanged) -----------
__global__ __launch_bounds__(256) void gather_kernel(const uint4* __restrict__ h4,
                                                     const float* __restrict__ ci,
                                                     const int* __restrict__ offsets,
                                                     const int* __restrict__ bin_src,
                                                     float* __restrict__ out) {
    int node = blockIdx.x * 16 + (threadIdx.x >> 4);
    int lane = threadIdx.x & 15;
    if (node >= N_NODES) return;

    int beg = offsets[node];
    int end = offsets[node + 1];

    float acc[8] = {};
    int i = beg;
    for (; i + 4 <= end; i += 4) {
        int s0 = bin_src[i + 0];
        int s1 = bin_src[i + 1];
        int s2 = bin_src[i + 2];
        int s3 = bin_src[i + 3];
        uint4 v0 = h4[(size_t)s0 * 16 + lane];
        uint4 v1 = h4[(size_t)s1 * 16 + lane];
        uint4 v2 = h4[(size_t)s2 * 16 + lane];
        uint4 v3 = h4[(size_t)s3 * 16 + lane];
        acc[0] += (bf_lo(v0.x) + bf_lo(v1.x)) + (bf_lo(v2.x) + bf_lo(v3.x));
        acc[1] += (bf_hi(v0.x) + bf_hi(v1.x)) + (bf_hi(v2.x) + bf_hi(v3.x));
        acc[2] += (bf_lo(v0.y) + bf_lo(v1.y)) + (bf_lo(v2.y) + bf_lo(v3.y));
        acc[3] += (bf_hi(v0.y) + bf_hi(v1.y)) + (bf_hi(v2.y) + bf_hi(v3.y));
        acc[4] += (bf_lo(v0.z) + bf_lo(v1.z)) + (bf_lo(v2.z) + bf_lo(v3.z));
        acc[5] += (bf_hi(v0.z) + bf_hi(v1.z)) + (bf_hi(v2.z) + bf_hi(v3.z));
        acc[6] += (bf_lo(v0.w) + bf_lo(v1.w)) + (bf_lo(v2.w) + bf_lo(v3.w));
        acc[7] += (bf_hi(v0.w) + bf_hi(v1.w)) + (bf_hi(v2.w) + bf_hi(v3.w));
    }
    for (; i < end; ++i) {
        int s = bin_src[i];
        uint4 v = h4[(size_t)s * 16 + lane];
        acc[0] += bf_lo(v.x); acc[1] += bf_hi(v.x);
        acc[2] += bf_lo(v.y); acc[3] += bf_hi(v.y);
        acc[4] += bf_lo(v.z); acc[5] += bf_hi(v.z);
        acc[6] += bf_lo(v.w); acc[7] += bf_hi(v.w);
    }
    float sc = ci[node];
    float4 o0 = make_float4(acc[0] * sc, acc[1] * sc, acc[2] * sc, acc[3] * sc);
    float4 o1 = make_float4(acc[4] * sc, acc[5] * sc, acc[6] * sc, acc[7] * sc);
    float4* o4 = reinterpret_cast<float4*>(out) + (size_t)node * 32 + lane * 2;
    o4[0] = o0;
    o4[1] = o1;
}

extern "C" void kernel_launch(void* const* d_in, const int* in_sizes, int n_in,
                              void* d_out, int out_size, void* d_ws, size_t ws_size,
                              hipStream_t stream) {
    const float* feat = (const float*)d_in[0];
    const float* W    = (const float*)d_in[1];
    const float* cj   = (const float*)d_in[2];
    const float* ci   = (const float*)d_in[3];
    const int*   src  = (const int*)d_in[4];
    const int*   dst  = (const int*)d_in[5];
    float* out = (float*)d_out;

    const size_t H_BYTES    = (size_t)N_NODES * OUT_F * 2;          // 25.6 MB
    const size_t WT_BYTES   = (size_t)IN_F * OUT_F * 2;             // 64 KB
    const size_t OFF_BYTES  = (((size_t)(N_NODES + 1) * 4) + 15) & ~(size_t)15;
    const size_t BC_BYTES   = (((size_t)BUCKETS * 4) + 15) & ~(size_t)15;
    const size_t SLAB_BYTES = (size_t)BUCKETS * CAP * 4;            // 8 MB (packed)

    char* ws = (char*)d_ws;
    unsigned short* h     = (unsigned short*)ws;  ws += H_BYTES;
    unsigned short* Wfrag = (unsigned short*)ws;  ws += WT_BYTES;
    int* offsets        = (int*)ws;           ws += OFF_BYTES;
    int* bucket_cursor  = (int*)ws;           ws += BC_BYTES;
    unsigned int* slab  = (unsigned int*)ws;  ws += SLAB_BYTES;
    int* bin_src        = (int*)ws;

    hipMemsetAsync(bucket_cursor, 0, (size_t)BUCKETS * 4, stream);

    part_kernel<<<NCHUNK, 512, 0, stream>>>(W, Wfrag, src, dst, bucket_cursor, slab);

    gemm_bin_kernel<<<GB_BLOCKS, 256, 0, stream>>>(feat, Wfrag, cj, h, slab,
                                                   bucket_cursor, offsets, bin_src);

    gather_kernel<<<(N_NODES + 15) / 16, 256, 0, stream>>>((const uint4*)h, ci, offsets, bin_src, out);
}

// Round 17
// 118.525 us; speedup vs baseline: 1.4672x; 1.0153x over previous
//
#include <hip/hip_runtime.h>

#define N_NODES 100000
#define N_EDGES 1600000
#define IN_F 256
#define OUT_F 128
#define E4 (N_EDGES / 4)

#define BUCKETS 256
#define NPB 391                        // 256*391 = 100096 >= N_NODES
#define CH 8192
#define NCHUNK ((N_EDGES + CH - 1) / CH)   // 196
#define CAP 8192                       // slab capacity/bucket (mean 6250, +24 sd)

#define GEMM_BLOCKS 1563               // 1563 * 64 rows = 100032 >= N_NODES
#define GB_BLOCKS (GEMM_BLOCKS + BUCKETS)  // 1819

typedef short bf16x8 __attribute__((ext_vector_type(8)));
typedef float f32x4 __attribute__((ext_vector_type(4)));

// ---- bf16 helpers (RNE) ----
__device__ __forceinline__ unsigned int f2bf(float f) {
    unsigned int u = __float_as_uint(f);
    return (u + 0x7FFFu + ((u >> 16) & 1u)) >> 16;
}
__device__ __forceinline__ unsigned int pack2(float a, float b) {
    return f2bf(a) | (f2bf(b) << 16);
}
__device__ __forceinline__ float bf_lo(unsigned int u) { return __uint_as_float(u << 16); }
__device__ __forceinline__ float bf_hi(unsigned int u) { return __uint_as_float(u & 0xFFFF0000u); }

// ---------------- P1: partition (+Wfrag prep in first 64 blocks) --------------
// Wfrag KT-MAJOR: idx = ((kt*8 + f)*64 + lane)*8 + j; one K-chunk (2 kt) = 16KB.
__global__ __launch_bounds__(512) void part_kernel(const float* __restrict__ W,
                                                   unsigned short* __restrict__ Wfrag,
                                                   const int* __restrict__ src,
                                                   const int* __restrict__ dst,
                                                   int* __restrict__ bucket_cursor,
                                                   unsigned int* __restrict__ slab) {
    __shared__ int hist[256];
    __shared__ int hstart[256];
    __shared__ int gbase[256];
    __shared__ unsigned int stage[CH];      // 32 KB
    __shared__ unsigned char bstage[CH];    // 8 KB

    const int bid = blockIdx.x;
    const int t = threadIdx.x;

    if (bid < 64) {
        int idx = bid * 512 + t;
        int j    = idx & 7;
        int lane = (idx >> 3) & 63;
        int ktf  = idx >> 9;
        int kt   = ktf >> 3;
        int f    = ktf & 7;
        int c    = f * 16 + (lane & 15);
        int k    = kt * 32 + (lane >> 4) * 8 + j;
        Wfrag[idx] = (unsigned short)f2bf(W[k * OUT_F + c]);
    }

    const int e0 = bid * CH;
    int nE = N_EDGES - e0;
    if (nE > CH) nE = CH;
    if (nE < 0) nE = 0;

    if (t < 256) hist[t] = 0;
    __syncthreads();

    int bb[16], rr[16];
    unsigned int pp[16];
    const int4* d4 = reinterpret_cast<const int4*>(dst);
    const int4* s4 = reinterpret_cast<const int4*>(src);
    #pragma unroll
    for (int i = 0; i < 4; ++i) {
        int li = t + i * 512;
        if (li * 4 < nE) {
            int4 d = d4[(e0 >> 2) + li];
            int4 s = s4[(e0 >> 2) + li];
            int b0 = d.x / NPB, b1 = d.y / NPB, b2 = d.z / NPB, b3 = d.w / NPB;
            bb[i*4+0] = b0; pp[i*4+0] = ((unsigned)(d.x - b0 * NPB) << 17) | (unsigned)s.x;
            bb[i*4+1] = b1; pp[i*4+1] = ((unsigned)(d.y - b1 * NPB) << 17) | (unsigned)s.y;
            bb[i*4+2] = b2; pp[i*4+2] = ((unsigned)(d.z - b2 * NPB) << 17) | (unsigned)s.z;
            bb[i*4+3] = b3; pp[i*4+3] = ((unsigned)(d.w - b3 * NPB) << 17) | (unsigned)s.w;
            rr[i*4+0] = atomicAdd(&hist[b0], 1);
            rr[i*4+1] = atomicAdd(&hist[b1], 1);
            rr[i*4+2] = atomicAdd(&hist[b2], 1);
            rr[i*4+3] = atomicAdd(&hist[b3], 1);
        } else {
            bb[i*4+0] = -1; bb[i*4+1] = -1; bb[i*4+2] = -1; bb[i*4+3] = -1;
        }
    }
    __syncthreads();

    int v = 0;
    if (t < 256) { v = hist[t]; hstart[t] = v; }
    __syncthreads();
    #pragma unroll
    for (int off = 1; off < 256; off <<= 1) {
        int u = 0;
        if (t < 256 && t >= off) u = hstart[t - off];
        __syncthreads();
        if (t < 256) hstart[t] += u;
        __syncthreads();
    }
    if (t < 256) {
        int ex = hstart[t] - v;
        if (v > 0) gbase[t] = atomicAdd(&bucket_cursor[t], v);
        hstart[t] = ex;
    }
    __syncthreads();

    #pragma unroll
    for (int i = 0; i < 16; ++i) {
        if (bb[i] >= 0) {
            int pos = hstart[bb[i]] + rr[i];
            stage[pos] = pp[i];
            bstage[pos] = (unsigned char)bb[i];
        }
    }
    __syncthreads();

    for (int idx = t; idx < nE; idx += 512) {
        int b = bstage[idx];
        slab[(size_t)b * CAP + gbase[b] + (idx - hstart[b])] = stage[idx];
    }
}

// ---------------- Fused: MFMA gemm (bids 0..1562) + bin (bids 1563..1818) -----
// gemm role: 256 thr = 4 waves, 64 rows. __launch_bounds__(256,8) caps VGPR at
//   64 -> 32 waves/CU (2x r16). Feat prefetched ONE kt ahead (2 float4 = 8
//   VGPR) to fit the budget; W staged per 2-kt chunk (16KB) from Wfrag; wout
//   aliases wl. LDS 17.4KB.
// bin role: unchanged (packed slab).
__global__ __launch_bounds__(256, 8) void gemm_bin_kernel(const float* __restrict__ feat,
                                                          const unsigned short* __restrict__ Wfrag,
                                                          const float* __restrict__ cj,
                                                          unsigned short* __restrict__ h,
                                                          const unsigned int* __restrict__ slab,
                                                          const int* __restrict__ bucket_cursor,
                                                          int* __restrict__ offsets,
                                                          int* __restrict__ bin_src) {
    __shared__ __align__(16) char pool[4 * 16 * 136 * 2];   // 17408 B

    const int bid = blockIdx.x;
    const int tid = threadIdx.x;

    if (bid >= GEMM_BLOCKS) {
        // ---- bin role ----
        int* hist = (int*)pool;
        int* cur  = hist + 392;
        int* sbuf = cur + 392;
        int* gbsz = sbuf + 256;

        const int b = bid - GEMM_BLOCKS;
        const int nlo = b * NPB;
        int nn = N_NODES - nlo;
        if (nn > NPB) nn = NPB;

        int v = bucket_cursor[tid];
        sbuf[tid] = v;
        __syncthreads();
        #pragma unroll
        for (int off = 1; off < 256; off <<= 1) {
            int u = (tid >= off) ? sbuf[tid - off] : 0;
            __syncthreads();
            sbuf[tid] += u;
            __syncthreads();
        }
        if (tid == b) { gbsz[0] = sbuf[tid] - v; gbsz[1] = v; }
        if (b == 0 && tid == 0) offsets[N_NODES] = N_EDGES;
        __syncthreads();
        const int gb = gbsz[0];
        const int sz = gbsz[1];
        const unsigned int* sl = slab + (size_t)b * CAP;

        for (int j = tid; j < 392; j += 256) hist[j] = 0;
        __syncthreads();

        for (int i = tid; i < sz; i += 256) atomicAdd(&hist[sl[i] >> 17], 1);
        __syncthreads();

        int a0 = 0, a1 = 0;
        if (tid < 196) { a0 = hist[2 * tid]; a1 = hist[2 * tid + 1]; }
        int part = a0 + a1;
        sbuf[tid] = part;
        __syncthreads();
        #pragma unroll
        for (int off = 1; off < 256; off <<= 1) {
            int u = (tid >= off) ? sbuf[tid - off] : 0;
            __syncthreads();
            sbuf[tid] += u;
            __syncthreads();
        }
        int ex = sbuf[tid] - part;
        if (tid < 196) {
            int o0 = gb + ex;
            int o1 = o0 + a0;
            if (2 * tid < nn)     { offsets[nlo + 2 * tid]     = o0; cur[2 * tid]     = o0; }
            if (2 * tid + 1 < nn) { offsets[nlo + 2 * tid + 1] = o1; cur[2 * tid + 1] = o1; }
        }
        __syncthreads();

        for (int i = tid; i < sz; i += 256) {
            unsigned int p = sl[i];
            int pos = atomicAdd(&cur[p >> 17], 1);
            bin_src[pos] = (int)(p & 0x1FFFFu);
        }
        return;
    }

    // ---- gemm role: 64 rows, 4 waves x 16 rows, per-kt feat prefetch ----
    unsigned short* wl = (unsigned short*)pool;   // 16 KB (aliased by wout later)
    const int wave = tid >> 6;
    const int lane = tid & 63;
    const int r  = lane & 15;
    const int kq = lane >> 4;
    const int rowbase = bid * 64 + wave * 16;

    int arow = rowbase + r;
    if (arow >= N_NODES) arow = N_NODES - 1;
    const float4* fr4 = reinterpret_cast<const float4*>(feat + (size_t)arow * IN_F);

    f32x4 acc[8];
    #pragma unroll
    for (int f = 0; f < 8; ++f) acc[f] = (f32x4){0.f, 0.f, 0.f, 0.f};

    // prefetch kt=0 feat (2 float4 = 8 VGPR)
    float4 fv0 = fr4[kq * 2];
    float4 fv1 = fr4[kq * 2 + 1];

    const uint4* wsrc = reinterpret_cast<const uint4*>(Wfrag);
    uint4* wdst = reinterpret_cast<uint4*>(wl);

    #pragma unroll
    for (int kt = 0; kt < 8; ++kt) {
        if ((kt & 1) == 0) {
            if (kt > 0) __syncthreads();   // prior chunk's wl reads done
            // stage chunk kt/2: 16KB (1024 uint4 across 256 thr)
            #pragma unroll
            for (int i = 0; i < 4; ++i)
                wdst[tid + i * 256] = wsrc[(kt >> 1) * 1024 + tid + i * 256];
        }

        // pack current kt's a-frag
        bf16x8 a;
        {
            uint4 au;
            au.x = pack2(fv0.x, fv0.y);
            au.y = pack2(fv0.z, fv0.w);
            au.z = pack2(fv1.x, fv1.y);
            au.w = pack2(fv1.z, fv1.w);
            a = *reinterpret_cast<bf16x8*>(&au);
        }

        // prefetch next kt's feat (in flight under MFMAs)
        if (kt < 7) {
            fv0 = fr4[(kt + 1) * 8 + kq * 2];
            fv1 = fr4[(kt + 1) * 8 + kq * 2 + 1];
        }

        if ((kt & 1) == 0) __syncthreads();  // wl staged

        const int half = (kt & 1) * 8;
        #pragma unroll
        for (int f = 0; f < 8; ++f) {
            bf16x8 b = *reinterpret_cast<const bf16x8*>(&wl[((half + f) * 64 + lane) * 8]);
            acc[f] = __builtin_amdgcn_mfma_f32_16x16x32_bf16(a, b, acc[f], 0, 0, 0);
        }
    }

    int orow[4]; float cjv[4];
    #pragma unroll
    for (int i = 0; i < 4; ++i) {
        orow[i] = rowbase + kq * 4 + i;
        cjv[i] = cj[orow[i] < N_NODES ? orow[i] : 0];
    }

    __syncthreads();   // all wl reads done; reuse pool as wout
    unsigned short* wout = (unsigned short*)pool + wave * (16 * 136);
    #pragma unroll
    for (int f = 0; f < 8; ++f) {
        #pragma unroll
        for (int i = 0; i < 4; ++i) {
            wout[(kq * 4 + i) * 136 + f * 16 + r] =
                (unsigned short)f2bf(acc[f][i] * cjv[i]);
        }
    }
    __syncthreads();

    {
        int row = lane >> 2;
        int ch  = lane & 3;
        int grow = rowbase + row;
        if (grow < N_NODES) {
            uint4* hv = reinterpret_cast<uint4*>(h);
            #pragma unroll
            for (int j = 0; j < 4; ++j) {
                uint4 vv = *reinterpret_cast<const uint4*>(
                    (const char*)wout + row * 272 + (ch + 4 * j) * 16);
                hv[(size_t)grow * 16 + ch + 4 * j] = vv;
            }
        }
    }
}

// ---------------- Gather: 16 lanes/node, uint4 per lane (unchanged) -----------
__global__ __launch_bounds__(256) void gather_kernel(const uint4* __restrict__ h4,
                                                     const float* __restrict__ ci,
                                                     const int* __restrict__ offsets,
                                                     const int* __restrict__ bin_src,
                                                     float* __restrict__ out) {
    int node = blockIdx.x * 16 + (threadIdx.x >> 4);
    int lane = threadIdx.x & 15;
    if (node >= N_NODES) return;

    int beg = offsets[node];
    int end = offsets[node + 1];

    float acc[8] = {};
    int i = beg;
    for (; i + 4 <= end; i += 4) {
        int s0 = bin_src[i + 0];
        int s1 = bin_src[i + 1];
        int s2 = bin_src[i + 2];
        int s3 = bin_src[i + 3];
        uint4 v0 = h4[(size_t)s0 * 16 + lane];
        uint4 v1 = h4[(size_t)s1 * 16 + lane];
        uint4 v2 = h4[(size_t)s2 * 16 + lane];
        uint4 v3 = h4[(size_t)s3 * 16 + lane];
        acc[0] += (bf_lo(v0.x) + bf_lo(v1.x)) + (bf_lo(v2.x) + bf_lo(v3.x));
        acc[1] += (bf_hi(v0.x) + bf_hi(v1.x)) + (bf_hi(v2.x) + bf_hi(v3.x));
        acc[2] += (bf_lo(v0.y) + bf_lo(v1.y)) + (bf_lo(v2.y) + bf_lo(v3.y));
        acc[3] += (bf_hi(v0.y) + bf_hi(v1.y)) + (bf_hi(v2.y) + bf_hi(v3.y));
        acc[4] += (bf_lo(v0.z) + bf_lo(v1.z)) + (bf_lo(v2.z) + bf_lo(v3.z));
        acc[5] += (bf_hi(v0.z) + bf_hi(v1.z)) + (bf_hi(v2.z) + bf_hi(v3.z));
        acc[6] += (bf_lo(v0.w) + bf_lo(v1.w)) + (bf_lo(v2.w) + bf_lo(v3.w));
        acc[7] += (bf_hi(v0.w) + bf_hi(v1.w)) + (bf_hi(v2.w) + bf_hi(v3.w));
    }
    for (; i < end; ++i) {
        int s = bin_src[i];
        uint4 v = h4[(size_t)s * 16 + lane];
        acc[0] += bf_lo(v.x); acc[1] += bf_hi(v.x);
        acc[2] += bf_lo(v.y); acc[3] += bf_hi(v.y);
        acc[4] += bf_lo(v.z); acc[5] += bf_hi(v.z);
        acc[6] += bf_lo(v.w); acc[7] += bf_hi(v.w);
    }
    float sc = ci[node];
    float4 o0 = make_float4(acc[0] * sc, acc[1] * sc, acc[2] * sc, acc[3] * sc);
    float4 o1 = make_float4(acc[4] * sc, acc[5] * sc, acc[6] * sc, acc[7] * sc);
    float4* o4 = reinterpret_cast<float4*>(out) + (size_t)node * 32 + lane * 2;
    o4[0] = o0;
    o4[1] = o1;
}

extern "C" void kernel_launch(void* const* d_in, const int* in_sizes, int n_in,
                              void* d_out, int out_size, void* d_ws, size_t ws_size,
                              hipStream_t stream) {
    const float* feat = (const float*)d_in[0];
    const float* W    = (const float*)d_in[1];
    const float* cj   = (const float*)d_in[2];
    const float* ci   = (const float*)d_in[3];
    const int*   src  = (const int*)d_in[4];
    const int*   dst  = (const int*)d_in[5];
    float* out = (float*)d_out;

    const size_t H_BYTES    = (size_t)N_NODES * OUT_F * 2;          // 25.6 MB
    const size_t WT_BYTES   = (size_t)IN_F * OUT_F * 2;             // 64 KB
    const size_t OFF_BYTES  = (((size_t)(N_NODES + 1) * 4) + 15) & ~(size_t)15;
    const size_t BC_BYTES   = (((size_t)BUCKETS * 4) + 15) & ~(size_t)15;
    const size_t SLAB_BYTES = (size_t)BUCKETS * CAP * 4;            // 8 MB (packed)

    char* ws = (char*)d_ws;
    unsigned short* h     = (unsigned short*)ws;  ws += H_BYTES;
    unsigned short* Wfrag = (unsigned short*)ws;  ws += WT_BYTES;
    int* offsets        = (int*)ws;           ws += OFF_BYTES;
    int* bucket_cursor  = (int*)ws;           ws += BC_BYTES;
    unsigned int* slab  = (unsigned int*)ws;  ws += SLAB_BYTES;
    int* bin_src        = (int*)ws;

    hipMemsetAsync(bucket_cursor, 0, (size_t)BUCKETS * 4, stream);

    part_kernel<<<NCHUNK, 512, 0, stream>>>(W, Wfrag, src, dst, bucket_cursor, slab);

    gemm_bin_kernel<<<GB_BLOCKS, 256, 0, stream>>>(feat, Wfrag, cj, h, slab,
                                                   bucket_cursor, offsets, bin_src);

    gather_kernel<<<(N_NODES + 15) / 16, 256, 0, stream>>>((const uint4*)h, ci, offsets, bin_src, out);
}